// Round 7
// baseline (1169.462 us; speedup 1.0000x reference)
//
#include <hip/hip_runtime.h>
#include <math.h>

#define D 64
#define RELS 8

__device__ __forceinline__ float lrelu(float e){ return e > 0.f ? e : 0.2f*e; }
__device__ __forceinline__ unsigned fenc(float f){
  unsigned u = __float_as_uint(f);
  return (u & 0x80000000u) ? ~u : (u | 0x80000000u);
}
__device__ __forceinline__ float fdec(unsigned u){
  return (u & 0x80000000u) ? __uint_as_float(u & 0x7fffffffu) : __uint_as_float(~u);
}

// ---- knode: per-block compute v (W_r@a_src, W_r@a_dst) in LDS, then per-node
// logits s,d for all relations (layout [rel*N + n])
__global__ void knode(const float* __restrict__ x, const float* __restrict__ W,
                      const float* __restrict__ a_src, const float* __restrict__ a_dst,
                      float* __restrict__ s_all, float* __restrict__ d_all, int N){
  __shared__ float vs[2*RELS*D];
  int t = threadIdx.x;
  #pragma unroll
  for (int i = 0; i < 4; ++i){
    int e = t + i*256;
    int dir = e >> 9, r = (e >> 6) & 7, col = e & 63;
    const float* Wrow = W + (size_t)r*D*D + (size_t)col*D;
    const float* av = (dir ? a_dst : a_src) + r*D;
    float acc = 0.f;
    for (int f = 0; f < D; f += 4){
      float4 wv = *(const float4*)(Wrow + f);
      float4 aa = *(const float4*)(av + f);
      acc += wv.x*aa.x + wv.y*aa.y + wv.z*aa.z + wv.w*aa.w;
    }
    vs[e] = acc;
  }
  __syncthreads();
  int n = blockIdx.x*blockDim.x + t;
  if (n >= N) return;
  float s[RELS], dd[RELS];
  #pragma unroll
  for (int r = 0; r < RELS; ++r){ s[r] = 0.f; dd[r] = 0.f; }
  const float* xr = x + (size_t)n*D;
  for (int k = 0; k < D; k += 4){
    float4 xv = *(const float4*)(xr + k);
    #pragma unroll
    for (int r = 0; r < RELS; ++r){
      s[r]  += xv.x*vs[r*D+k]   + xv.y*vs[r*D+k+1]   + xv.z*vs[r*D+k+2]   + xv.w*vs[r*D+k+3];
      dd[r] += xv.x*vs[512+r*D+k] + xv.y*vs[512+r*D+k+1]
             + xv.z*vs[512+r*D+k+2] + xv.w*vs[512+r*D+k+3];
    }
  }
  #pragma unroll
  for (int r = 0; r < RELS; ++r){
    s_all[(size_t)r*N + n] = s[r];
    d_all[(size_t)r*N + n] = dd[r];
  }
}

// ---- khist: count edges per coarse key = rel*NT + (dst>>6)
__global__ void khist(const int* __restrict__ dst, const int* __restrict__ et,
                      int* __restrict__ hist, int E, int NT){
  int stride = gridDim.x*blockDim.x;
  for (int i = blockIdx.x*blockDim.x+threadIdx.x; i < E; i += stride)
    atomicAdd(&hist[et[i]*NT + (dst[i]>>6)], 1);
}

// ---- 3-kernel exclusive scan of hist[0..NK) into off[0..NK], off[0]=0; cur=off copy
__global__ void kscan1(const int* __restrict__ hist, int* __restrict__ off,
                       int* __restrict__ bsums, int NK){
  __shared__ int tot[256];
  int b = blockIdx.x, t = threadIdx.x;
  int base = b*2048 + t*8;
  int v[8]; int c = 0;
  #pragma unroll
  for (int j = 0; j < 8; ++j){ int idx = base+j; int h = (idx<NK)? hist[idx]:0; c += h; v[j] = c; }
  tot[t] = c; __syncthreads();
  for (int o = 1; o < 256; o <<= 1){
    int add = (t >= o) ? tot[t-o] : 0;
    __syncthreads();
    tot[t] += add;
    __syncthreads();
  }
  int excl = (t == 0) ? 0 : tot[t-1];
  if (t == 255) bsums[b] = tot[255];
  #pragma unroll
  for (int j = 0; j < 8; ++j){ int idx = base+j; if (idx < NK) off[idx+1] = v[j] + excl; }
}

__global__ void kscan2(int* __restrict__ bsums, int NB){
  __shared__ int s[512];
  int t = threadIdx.x;
  s[t] = (t < NB) ? bsums[t] : 0;
  __syncthreads();
  for (int o = 1; o < 512; o <<= 1){
    int add = (t >= o) ? s[t-o] : 0;
    __syncthreads();
    s[t] += add;
    __syncthreads();
  }
  if (t < NB) bsums[t] = (t == 0) ? 0 : s[t-1];
}

__global__ void kscan3(int* __restrict__ off, int* __restrict__ cur,
                       const int* __restrict__ bsums, int NK){
  int b = blockIdx.x, t = threadIdx.x;
  int add = bsums[b];
  int base = b*2048 + t*8;
  #pragma unroll
  for (int j = 0; j < 8; ++j){
    int id1 = base+j+1;
    if (id1 <= NK){
      int nv = off[id1] + add;
      off[id1] = nv;
      if (id1 < NK) cur[id1] = nv;
    }
  }
  if (b == 0 && t == 0){ off[0] = 0; cur[0] = 0; }
}

// ---- kscatter: counting-sort placement; record = {(dl<<26)|src, logit_bits}
__global__ void kscatter(const int* __restrict__ src, const int* __restrict__ dst,
                         const int* __restrict__ et, const float* __restrict__ s_all,
                         const float* __restrict__ d_all, int* __restrict__ cur,
                         int2* __restrict__ rec, int E, int N, int NT){
  int stride = gridDim.x*blockDim.x;
  for (int i = blockIdx.x*blockDim.x+threadIdx.x; i < E; i += stride){
    int r = et[i], dn = dst[i], sn = src[i];
    int pos = atomicAdd(&cur[r*NT + (dn>>6)], 1);
    float lg = lrelu(s_all[(size_t)r*N + sn] + d_all[(size_t)r*N + dn]);
    rec[pos] = make_int2(((dn & 63) << 26) | sn, __float_as_int(lg));
  }
}

// ---- kmega: 512 threads (wave w <-> rel w); 8 ag tiles + x tile in LDS.
// Phases: init -> edge max -> edge den -> edge gather/scatter -> row scale -> 9 GEMMs.
__global__ __launch_bounds__(512, 1) void kmega(
    const float* __restrict__ x, const float* __restrict__ W,
    const float* __restrict__ W_self, const float* __restrict__ b_self,
    const float* __restrict__ bias, const float* __restrict__ s_all,
    const float* __restrict__ d_all, const int* __restrict__ off,
    const int2* __restrict__ rec, float* __restrict__ out, int N, int NT){
  __shared__ float ag[RELS][64][68];   // 139264 B
  __shared__ float xs[64][68];         //  17408 B
  __shared__ unsigned mrow[RELS*64];   //   2048 B
  __shared__ float den[RELS*64];       //   2048 B  -> total 160768 <= 160 KiB

  int t = threadIdx.x;
  int b = blockIdx.x;
  int row0 = b * 64;
  int w = t >> 6;          // wave index == relation
  int ln = t & 63;         // owned dst-local row

  // phase 0: zero ag, load x tile, init mrow/den with self term
  float4 z4 = make_float4(0.f,0.f,0.f,0.f);
  float* agf = &ag[0][0][0];
  #pragma unroll
  for (int i = 0; i < 17; ++i) *(float4*)(agf + (size_t)(t + i*512)*4) = z4;
  #pragma unroll
  for (int i = 0; i < 2; ++i){
    int idx4 = t + i*512;
    int row = idx4 >> 4, col4 = (idx4 & 15)*4;
    float4 v = z4;
    if (row0 + row < N) v = *(const float4*)(x + (size_t)(row0+row)*D + col4);
    *(float4*)(&xs[row][col4]) = v;
  }
  int n = row0 + ln;
  float eself = 0.f;
  if (n < N) eself = lrelu(s_all[(size_t)w*N + n] + d_all[(size_t)w*N + n]);
  mrow[t] = fenc(eself);
  den[t] = 0.f;
  __syncthreads();

  int e0 = off[w*NT + b], e1 = off[w*NT + b + 1];

  // phase 1: segment max (LDS atomicMax, thread-per-edge)
  for (int i = e0 + ln; i < e1; i += 64){
    int2 rc = rec[i];
    int dl = ((unsigned)rc.x) >> 26;
    atomicMax(&mrow[(w<<6) + dl], fenc(__int_as_float(rc.y)));
  }
  __syncthreads();

  // phase 2: denominators (thread-per-edge, recs L1-hot)
  for (int i = e0 + ln; i < e1; i += 64){
    int2 rc = rec[i];
    int dl = ((unsigned)rc.x) >> 26;
    float wgt = __expf(__int_as_float(rc.y) - fdec(mrow[(w<<6) + dl]));
    atomicAdd(&den[(w<<6) + dl], wgt);
  }
  __syncthreads();

  // phase 3: weighted gather/scatter, 16-lane subgroup per edge, 8-deep
  {
    int slice = (t >> 4) & 3;
    int l4 = (t & 15) * 4;
    int len = e1 - e0;
    int q = len >> 2, rm = len & 3;
    int c0 = e0 + slice*q + min(slice, rm);
    int c1e = c0 + q + (slice < rm ? 1 : 0);
    for (int i0 = c0; i0 < c1e; i0 += 8){
      int lim = c1e - 1;
      int sn[8]; int dl[8]; float al[8];
      #pragma unroll
      for (int j = 0; j < 8; ++j){
        int i = min(i0 + j, lim);
        int2 rc = rec[i];
        sn[j] = rc.x & 0x3FFFFFF;
        dl[j] = ((unsigned)rc.x) >> 26;
        al[j] = __int_as_float(rc.y);
      }
      #pragma unroll
      for (int j = 0; j < 8; ++j)
        al[j] = __expf(al[j] - fdec(mrow[(w<<6) + dl[j]]));
      float4 xv[8];
      #pragma unroll
      for (int j = 0; j < 8; ++j)
        xv[j] = *(const float4*)(x + (size_t)sn[j]*D + l4);
      #pragma unroll
      for (int j = 0; j < 8; ++j){
        if (i0 + j <= lim){
          float* p = &ag[w][dl[j]][l4];
          atomicAdd(p+0, al[j]*xv[j].x);
          atomicAdd(p+1, al[j]*xv[j].y);
          atomicAdd(p+2, al[j]*xv[j].z);
          atomicAdd(p+3, al[j]*xv[j].w);
        }
      }
    }
  }
  __syncthreads();

  // phase 4: per-row normalize + self term (owner thread per (rel,row))
  {
    float m = fdec(mrow[t]);
    float wself = __expf(eself - m);
    float inv = (n < N) ? 1.0f / (den[t] + wself) : 0.f;
    float cw = wself * inv;
    float* agr = &ag[w][ln][0];
    const float* xr = &xs[ln][0];
    #pragma unroll
    for (int c = 0; c < 64; c += 4){
      float4 a = *(const float4*)(agr + c);
      float4 xv = *(const float4*)(xr + c);
      a.x = a.x*inv + cw*xv.x;
      a.y = a.y*inv + cw*xv.y;
      a.z = a.z*inv + cw*xv.z;
      a.w = a.w*inv + cw*xv.w;
      *(float4*)(agr + c) = a;
    }
  }
  __syncthreads();

  // phase 5: 9 GEMMs, no barriers (all LDS read-only); B from global (L1/L2-hot)
  int tcol = (t & 15) * 4;
  int r0g = (t >> 4) * 2;
  float acc[2][4] = {};
  for (int rel = 0; rel <= RELS; ++rel){
    const float* A = (rel < RELS) ? &ag[rel][0][0] : &xs[0][0];
    const float* B = (rel < RELS) ? (W + (size_t)rel*D*D) : W_self;
    #pragma unroll 4
    for (int k4 = 0; k4 < 16; ++k4){
      int k = k4 << 2;
      float4 b0 = *(const float4*)(B + (k+0)*64 + tcol);
      float4 b1 = *(const float4*)(B + (k+1)*64 + tcol);
      float4 b2 = *(const float4*)(B + (k+2)*64 + tcol);
      float4 b3 = *(const float4*)(B + (k+3)*64 + tcol);
      #pragma unroll
      for (int j = 0; j < 2; ++j){
        float4 av = *(const float4*)(A + (size_t)(r0g+j)*68 + k);
        acc[j][0] += av.x*b0.x + av.y*b1.x + av.z*b2.x + av.w*b3.x;
        acc[j][1] += av.x*b0.y + av.y*b1.y + av.z*b2.y + av.w*b3.y;
        acc[j][2] += av.x*b0.z + av.y*b1.z + av.z*b2.z + av.w*b3.z;
        acc[j][3] += av.x*b0.w + av.y*b1.w + av.z*b2.w + av.w*b3.w;
      }
    }
  }

  // epilogue: bias sum + single out write
  float4 bb = *(const float4*)(b_self + tcol);
  #pragma unroll
  for (int r = 0; r < RELS; ++r){
    float4 bv = *(const float4*)(bias + r*D + tcol);
    bb.x += bv.x; bb.y += bv.y; bb.z += bv.z; bb.w += bv.w;
  }
  #pragma unroll
  for (int j = 0; j < 2; ++j){
    int nn = row0 + r0g + j;
    if (nn < N){
      float4 o = make_float4(acc[j][0]+bb.x, acc[j][1]+bb.y, acc[j][2]+bb.z, acc[j][3]+bb.w);
      *(float4*)(out + (size_t)nn*D + tcol) = o;
    }
  }
}

extern "C" void kernel_launch(void* const* d_in, const int* in_sizes, int n_in,
                              void* d_out, int out_size, void* d_ws, size_t ws_size,
                              hipStream_t stream) {
  const float* x      = (const float*)d_in[0];
  const int*   ei     = (const int*)d_in[1];
  const int*   et     = (const int*)d_in[2];
  const float* W_self = (const float*)d_in[3];
  const float* b_self = (const float*)d_in[4];
  const float* W      = (const float*)d_in[5];
  const float* a_src  = (const float*)d_in[6];
  const float* a_dst  = (const float*)d_in[7];
  const float* bias   = (const float*)d_in[8];

  int N = in_sizes[0] / D;
  int E = in_sizes[2];
  int NK = N * RELS;
  int NT = (N + 63) / 64;          // tiles
  int NKEY = RELS * NT;            // coarse sort keys
  float* out = (float*)d_out;

  float* ws    = (float*)d_ws;
  float* s_all = ws;                           // NK
  float* d_all = s_all + (size_t)NK;           // NK
  int* hist    = (int*)(d_all + (size_t)NK);   // NKEY
  int* off     = hist + (size_t)NKEY;          // NKEY+1 (+pad)
  int* cur     = off + (size_t)NKEY + 16;      // NKEY
  int* bsums   = cur + (size_t)NKEY;           // 512
  int2* rec    = (int2*)(bsums + 512);         // E (8B records)

  const int* srcp = ei;
  const int* dstp = ei + E;

  knode<<<(N + 255)/256, 256, 0, stream>>>(x, W, a_src, a_dst, s_all, d_all, N);

  hipMemsetAsync(hist, 0, (size_t)NKEY*sizeof(int), stream);
  khist<<<1024, 256, 0, stream>>>(dstp, et, hist, E, NT);

  int NB = (NKEY + 2047) / 2048;
  kscan1<<<NB, 256, 0, stream>>>(hist, off, bsums, NKEY);
  kscan2<<<1, 512, 0, stream>>>(bsums, NB);
  kscan3<<<NB, 256, 0, stream>>>(off, cur, bsums, NKEY);

  kscatter<<<2048, 256, 0, stream>>>(srcp, dstp, et, s_all, d_all, cur, rec, E, N, NT);

  kmega<<<NT, 512, 0, stream>>>(x, W, W_self, b_self, bias, s_all, d_all,
                                off, rec, out, N, NT);
}

// Round 9
// 1046.679 us; speedup vs baseline: 1.1173x; 1.1173x over previous
//
#include <hip/hip_runtime.h>
#include <math.h>

#define D 64
#define RELS 8

__device__ __forceinline__ float lrelu(float e){ return e > 0.f ? e : 0.2f*e; }

// ---- knode: per-node logits s,d for all rels; wself = exp(eself); den init = wself
__global__ void knode(const float* __restrict__ x, const float* __restrict__ W,
                      const float* __restrict__ a_src, const float* __restrict__ a_dst,
                      float* __restrict__ s_all, float* __restrict__ d_all,
                      float* __restrict__ wself, float* __restrict__ den, int N){
  __shared__ float vs[2*RELS*D];
  int t = threadIdx.x;
  #pragma unroll
  for (int i = 0; i < 4; ++i){
    int e = t + i*256;
    int dir = e >> 9, r = (e >> 6) & 7, col = e & 63;
    const float* Wrow = W + (size_t)r*D*D + (size_t)col*D;
    const float* av = (dir ? a_dst : a_src) + r*D;
    float acc = 0.f;
    for (int f = 0; f < D; f += 4){
      float4 wv = *(const float4*)(Wrow + f);
      float4 aa = *(const float4*)(av + f);
      acc += wv.x*aa.x + wv.y*aa.y + wv.z*aa.z + wv.w*aa.w;
    }
    vs[e] = acc;
  }
  __syncthreads();
  int n = blockIdx.x*blockDim.x + t;
  if (n >= N) return;
  float s[RELS], dd[RELS];
  #pragma unroll
  for (int r = 0; r < RELS; ++r){ s[r] = 0.f; dd[r] = 0.f; }
  const float* xr = x + (size_t)n*D;
  for (int k = 0; k < D; k += 4){
    float4 xv = *(const float4*)(xr + k);
    #pragma unroll
    for (int r = 0; r < RELS; ++r){
      s[r]  += xv.x*vs[r*D+k]   + xv.y*vs[r*D+k+1]   + xv.z*vs[r*D+k+2]   + xv.w*vs[r*D+k+3];
      dd[r] += xv.x*vs[512+r*D+k] + xv.y*vs[512+r*D+k+1]
             + xv.z*vs[512+r*D+k+2] + xv.w*vs[512+r*D+k+3];
    }
  }
  #pragma unroll
  for (int r = 0; r < RELS; ++r){
    float sv = s[r], dv = dd[r];
    s_all[(size_t)r*N + n] = sv;
    d_all[(size_t)r*N + n] = dv;
    float w = __expf(lrelu(sv + dv));
    wself[(size_t)r*N + n] = w;
    den[(size_t)r*N + n] = w;
  }
}

// ---- khist: count edges per coarse key = rel*NT + (dst>>6)
__global__ void khist(const int* __restrict__ dst, const int* __restrict__ et,
                      int* __restrict__ hist, int E, int NT){
  int stride = gridDim.x*blockDim.x;
  for (int i = blockIdx.x*blockDim.x+threadIdx.x; i < E; i += stride)
    atomicAdd(&hist[et[i]*NT + (dst[i]>>6)], 1);
}

// ---- 3-kernel exclusive scan: off[0..NK], off[0]=0; cur = copy
__global__ void kscan1(const int* __restrict__ hist, int* __restrict__ off,
                       int* __restrict__ bsums, int NK){
  __shared__ int tot[256];
  int b = blockIdx.x, t = threadIdx.x;
  int base = b*2048 + t*8;
  int v[8]; int c = 0;
  #pragma unroll
  for (int j = 0; j < 8; ++j){ int idx = base+j; int h = (idx<NK)? hist[idx]:0; c += h; v[j] = c; }
  tot[t] = c; __syncthreads();
  for (int o = 1; o < 256; o <<= 1){
    int add = (t >= o) ? tot[t-o] : 0;
    __syncthreads();
    tot[t] += add;
    __syncthreads();
  }
  int excl = (t == 0) ? 0 : tot[t-1];
  if (t == 255) bsums[b] = tot[255];
  #pragma unroll
  for (int j = 0; j < 8; ++j){ int idx = base+j; if (idx < NK) off[idx+1] = v[j] + excl; }
}

__global__ void kscan2(int* __restrict__ bsums, int NB){
  __shared__ int s[512];
  int t = threadIdx.x;
  s[t] = (t < NB) ? bsums[t] : 0;
  __syncthreads();
  for (int o = 1; o < 512; o <<= 1){
    int add = (t >= o) ? s[t-o] : 0;
    __syncthreads();
    s[t] += add;
    __syncthreads();
  }
  if (t < NB) bsums[t] = (t == 0) ? 0 : s[t-1];
}

__global__ void kscan3(int* __restrict__ off, int* __restrict__ cur,
                       const int* __restrict__ bsums, int NK){
  int b = blockIdx.x, t = threadIdx.x;
  int add = bsums[b];
  int base = b*2048 + t*8;
  #pragma unroll
  for (int j = 0; j < 8; ++j){
    int id1 = base+j+1;
    if (id1 <= NK){
      int nv = off[id1] + add;
      off[id1] = nv;
      if (id1 < NK) cur[id1] = nv;
    }
  }
  if (b == 0 && t == 0){ off[0] = 0; cur[0] = 0; }
}

// ---- kscatter: sort placement + u=exp(logit) + den accumulation
__global__ void kscatter(const int* __restrict__ src, const int* __restrict__ dst,
                         const int* __restrict__ et, const float* __restrict__ s_all,
                         const float* __restrict__ d_all, int* __restrict__ cur,
                         int2* __restrict__ meta, float* __restrict__ se,
                         float* __restrict__ den, int E, int N, int NT){
  int stride = gridDim.x*blockDim.x;
  for (int i = blockIdx.x*blockDim.x+threadIdx.x; i < E; i += stride){
    int r = et[i], dn = dst[i], sn = src[i];
    float e = lrelu(s_all[(size_t)r*N + sn] + d_all[(size_t)r*N + dn]);
    float u = __expf(e);
    int pos = atomicAdd(&cur[r*NT + (dn>>6)], 1);
    meta[pos] = make_int2(sn, r*N + dn);
    se[pos] = u;
    atomicAdd(&den[(size_t)r*N + dn], u);
  }
}

// ---- kagg: wave-per-edge weighted gather-scatter (lane = feature), 4-edge unroll
__global__ __launch_bounds__(256) void kagg(const int2* __restrict__ meta,
    const float* __restrict__ se, const float* __restrict__ x,
    float* __restrict__ agg, const int* __restrict__ off,
    int g0, int g1, int NT, int N){
  int tid = blockIdx.x*blockDim.x + threadIdx.x;
  int gw = tid >> 6, lane = tid & 63;
  int NW = (gridDim.x*blockDim.x) >> 6;
  int eb = off[g0*NT], ee = off[g1*NT];
  long aoff = -(long)g0 * N;
  for (int i0 = eb + gw*4; i0 < ee; i0 += NW*4){
    int lim = min(4, ee - i0);
    int2 m[4]; float u[4];
    #pragma unroll
    for (int j = 0; j < 4; ++j){
      int i = i0 + min(j, lim-1);
      m[j] = meta[i];
      u[j] = se[i];
    }
    float xv[4];
    #pragma unroll
    for (int j = 0; j < 4; ++j)
      xv[j] = x[(size_t)m[j].x*D + lane];
    #pragma unroll
    for (int j = 0; j < 4; ++j)
      if (j < lim)
        atomicAdd(&agg[((size_t)(m[j].y + aoff))*D + lane], u[j]*xv[j]);
  }
}

// ---- kgemm: per 64-row tile; stage normalized A=(agg+wself*x)/den via LDS dbuf;
// register-accumulate GEMMs over rels [g0,g1); first group adds self-term + bias.
__global__ __launch_bounds__(256) void kgemm(const float* __restrict__ x,
    const float* __restrict__ W, const float* __restrict__ W_self,
    const float* __restrict__ b_self, const float* __restrict__ bias,
    const float* __restrict__ wself, const float* __restrict__ den,
    const float* __restrict__ agg, float* __restrict__ out,
    int N, int g0, int g1, int first){
  __shared__ float xs[64][68];
  __shared__ float ab[2][64][68];
  int t = threadIdx.x;
  int row0 = blockIdx.x * 64;
  // staging mapping: 4 threads per row, 16 float-cols each
  int srow = t >> 2, scq = (t & 3) * 16;
  bool rv = (row0 + srow) < N;
  // gemm mapping
  int tcol = (t & 15) * 4, trow = (t >> 4) * 4;

  // stage x tile
  {
    float4 z4 = make_float4(0.f,0.f,0.f,0.f);
    const float* xp = x + (size_t)(row0+srow)*D + scq;
    #pragma unroll
    for (int j = 0; j < 4; ++j)
      *(float4*)(&xs[srow][scq + j*4]) = rv ? *(const float4*)(xp + j*4) : z4;
  }
  __syncthreads();

  float4 p0,p1,p2,p3; float pinv = 0.f, pcw = 0.f;
  // prefetch rel g0
  if (rv){
    int rn = g0*N + row0 + srow;
    float dn = den[rn];
    pinv = 1.0f / dn;
    pcw = wself[rn] * pinv;
    const float* ar = agg + ((size_t)(g0-g0)*N + row0 + srow)*D + scq;
    p0 = *(const float4*)(ar+0);  p1 = *(const float4*)(ar+4);
    p2 = *(const float4*)(ar+8);  p3 = *(const float4*)(ar+12);
  }
  // commit into ab[0]
  {
    float* dp = &ab[0][srow][scq];
    const float* xr = &xs[srow][scq];
    if (rv){
      #pragma unroll
      for (int c = 0; c < 4; ++c){
        float4 p = (c==0)?p0:(c==1)?p1:(c==2)?p2:p3;
        dp[c*4+0] = p.x*pinv + pcw*xr[c*4+0];
        dp[c*4+1] = p.y*pinv + pcw*xr[c*4+1];
        dp[c*4+2] = p.z*pinv + pcw*xr[c*4+2];
        dp[c*4+3] = p.w*pinv + pcw*xr[c*4+3];
      }
    } else {
      #pragma unroll
      for (int c = 0; c < 16; ++c) dp[c] = 0.f;
    }
  }
  __syncthreads();

  float acc[4][4] = {};
  int cur = 0;
  for (int r = g0; r < g1; ++r){
    bool hasnext = (r+1 < g1);
    // prefetch next rel to registers (overlaps with GEMM below)
    if (hasnext && rv){
      int rn = (r+1)*N + row0 + srow;
      float dn = den[rn];
      pinv = 1.0f / dn;
      pcw = wself[rn] * pinv;
      const float* ar = agg + ((size_t)(r+1-g0)*N + row0 + srow)*D + scq;
      p0 = *(const float4*)(ar+0);  p1 = *(const float4*)(ar+4);
      p2 = *(const float4*)(ar+8);  p3 = *(const float4*)(ar+12);
    }
    // GEMM accumulate: acc += ab[cur] @ W_r
    const float* B = W + (size_t)r*D*D;
    #pragma unroll 4
    for (int k4 = 0; k4 < 16; ++k4){
      int k = k4 << 2;
      float4 b0 = *(const float4*)(B + (k+0)*64 + tcol);
      float4 b1 = *(const float4*)(B + (k+1)*64 + tcol);
      float4 b2 = *(const float4*)(B + (k+2)*64 + tcol);
      float4 b3 = *(const float4*)(B + (k+3)*64 + tcol);
      #pragma unroll
      for (int j = 0; j < 4; ++j){
        float4 av = *(const float4*)(&ab[cur][trow+j][k]);
        acc[j][0] += av.x*b0.x + av.y*b1.x + av.z*b2.x + av.w*b3.x;
        acc[j][1] += av.x*b0.y + av.y*b1.y + av.z*b2.y + av.w*b3.y;
        acc[j][2] += av.x*b0.z + av.y*b1.z + av.z*b2.z + av.w*b3.z;
        acc[j][3] += av.x*b0.w + av.y*b1.w + av.z*b2.w + av.w*b3.w;
      }
    }
    if (hasnext){
      float* dp = &ab[cur^1][srow][scq];
      const float* xr = &xs[srow][scq];
      if (rv){
        #pragma unroll
        for (int c = 0; c < 4; ++c){
          float4 p = (c==0)?p0:(c==1)?p1:(c==2)?p2:p3;
          dp[c*4+0] = p.x*pinv + pcw*xr[c*4+0];
          dp[c*4+1] = p.y*pinv + pcw*xr[c*4+1];
          dp[c*4+2] = p.z*pinv + pcw*xr[c*4+2];
          dp[c*4+3] = p.w*pinv + pcw*xr[c*4+3];
        }
      } else {
        #pragma unroll
        for (int c = 0; c < 16; ++c) dp[c] = 0.f;
      }
    }
    __syncthreads();
    cur ^= 1;
  }

  if (first){
    // self-linear term (A = xs, B = W_self)
    #pragma unroll 4
    for (int k4 = 0; k4 < 16; ++k4){
      int k = k4 << 2;
      float4 b0 = *(const float4*)(W_self + (k+0)*64 + tcol);
      float4 b1 = *(const float4*)(W_self + (k+1)*64 + tcol);
      float4 b2 = *(const float4*)(W_self + (k+2)*64 + tcol);
      float4 b3 = *(const float4*)(W_self + (k+3)*64 + tcol);
      #pragma unroll
      for (int j = 0; j < 4; ++j){
        float4 av = *(const float4*)(&xs[trow+j][k]);
        acc[j][0] += av.x*b0.x + av.y*b1.x + av.z*b2.x + av.w*b3.x;
        acc[j][1] += av.x*b0.y + av.y*b1.y + av.z*b2.y + av.w*b3.y;
        acc[j][2] += av.x*b0.z + av.y*b1.z + av.z*b2.z + av.w*b3.z;
        acc[j][3] += av.x*b0.w + av.y*b1.w + av.z*b2.w + av.w*b3.w;
      }
    }
    float4 bb = *(const float4*)(b_self + tcol);
    #pragma unroll
    for (int r = 0; r < RELS; ++r){
      float4 bv = *(const float4*)(bias + r*D + tcol);
      bb.x += bv.x; bb.y += bv.y; bb.z += bv.z; bb.w += bv.w;
    }
    #pragma unroll
    for (int j = 0; j < 4; ++j){
      int n = row0 + trow + j;
      if (n < N){
        float4 o = make_float4(acc[j][0]+bb.x, acc[j][1]+bb.y, acc[j][2]+bb.z, acc[j][3]+bb.w);
        *(float4*)(out + (size_t)n*D + tcol) = o;
      }
    }
  } else {
    #pragma unroll
    for (int j = 0; j < 4; ++j){
      int n = row0 + trow + j;
      if (n < N){
        float* op = out + (size_t)n*D + tcol;
        float4 p = *(const float4*)op;
        float4 o = make_float4(p.x+acc[j][0], p.y+acc[j][1], p.z+acc[j][2], p.w+acc[j][3]);
        *(float4*)op = o;
      }
    }
  }
}

extern "C" void kernel_launch(void* const* d_in, const int* in_sizes, int n_in,
                              void* d_out, int out_size, void* d_ws, size_t ws_size,
                              hipStream_t stream) {
  const float* x      = (const float*)d_in[0];
  const int*   ei     = (const int*)d_in[1];
  const int*   et     = (const int*)d_in[2];
  const float* W_self = (const float*)d_in[3];
  const float* b_self = (const float*)d_in[4];
  const float* W      = (const float*)d_in[5];
  const float* a_src  = (const float*)d_in[6];
  const float* a_dst  = (const float*)d_in[7];
  const float* bias   = (const float*)d_in[8];

  int N = in_sizes[0] / D;
  int E = in_sizes[2];
  int NK = N * RELS;
  int NT = (N + 63) / 64;
  int NKEY = RELS * NT;
  float* out = (float*)d_out;

  float* ws    = (float*)d_ws;
  float* s_all = ws;                           // NK
  float* d_all = s_all + (size_t)NK;           // NK
  float* wself = d_all + (size_t)NK;           // NK
  float* den   = wself + (size_t)NK;           // NK
  int* hist    = (int*)(den + (size_t)NK);     // NKEY
  int* off     = hist + (size_t)NKEY;          // NKEY+1 (+pad)
  int* cur     = off + (size_t)NKEY + 16;      // NKEY
  int* bsums   = cur + (size_t)NKEY;           // 512
  int2* meta   = (int2*)(bsums + 512);         // E
  float* se    = (float*)(meta + (size_t)E);   // E
  float* agg   = se + (size_t)E;               // G * N * D

  size_t used = (size_t)((char*)agg - (char*)d_ws);
  size_t per_rel = (size_t)N * D * sizeof(float);
  int G = (int)((ws_size > used) ? ((ws_size - used) / per_rel) : 0);
  if (G < 1) G = 1;
  if (G > RELS) G = RELS;

  const int* srcp = ei;
  const int* dstp = ei + E;

  knode<<<(N + 255)/256, 256, 0, stream>>>(x, W, a_src, a_dst, s_all, d_all,
                                           wself, den, N);

  hipMemsetAsync(hist, 0, (size_t)NKEY*sizeof(int), stream);
  khist<<<1024, 256, 0, stream>>>(dstp, et, hist, E, NT);

  int NB = (NKEY + 2047) / 2048;
  kscan1<<<NB, 256, 0, stream>>>(hist, off, bsums, NKEY);
  kscan2<<<1, 512, 0, stream>>>(bsums, NB);
  kscan3<<<NB, 256, 0, stream>>>(off, cur, bsums, NKEY);

  kscatter<<<2048, 256, 0, stream>>>(srcp, dstp, et, s_all, d_all, cur,
                                     meta, se, den, E, N, NT);

  for (int g0 = 0; g0 < RELS; g0 += G){
    int g1 = min(g0 + G, RELS);
    hipMemsetAsync(agg, 0, (size_t)(g1-g0)*per_rel, stream);
    kagg<<<2048, 256, 0, stream>>>(meta, se, x, agg, off, g0, g1, NT, N);
    kgemm<<<NT, 256, 0, stream>>>(x, W, W_self, b_self, bias, wself, den,
                                  agg, out, N, g0, g1, (g0 == 0) ? 1 : 0);
  }
}

// Round 10
// 633.056 us; speedup vs baseline: 1.8473x; 1.6534x over previous
//
#include <hip/hip_runtime.h>
#include <math.h>

#define D 64
#define RELS 8

__device__ __forceinline__ float lrelu(float e){ return e > 0.f ? e : 0.2f*e; }
__device__ __forceinline__ unsigned short f2bf(float f){
  unsigned u = __float_as_uint(f);
  return (unsigned short)((u + 0x7FFFu + ((u >> 16) & 1u)) >> 16);
}
__device__ __forceinline__ float bf2f(unsigned short s){
  return __uint_as_float(((unsigned)s) << 16);
}

// ---- knode: per-node logits s,d for all rels; wself = exp(eself); den init = wself
__global__ void knode(const float* __restrict__ x, const float* __restrict__ W,
                      const float* __restrict__ a_src, const float* __restrict__ a_dst,
                      float* __restrict__ s_all, float* __restrict__ d_all,
                      float* __restrict__ wself, float* __restrict__ den, int N){
  __shared__ float vs[2*RELS*D];
  int t = threadIdx.x;
  #pragma unroll
  for (int i = 0; i < 4; ++i){
    int e = t + i*256;
    int dir = e >> 9, r = (e >> 6) & 7, col = e & 63;
    const float* Wrow = W + (size_t)r*D*D + (size_t)col*D;
    const float* av = (dir ? a_dst : a_src) + r*D;
    float acc = 0.f;
    for (int f = 0; f < D; f += 4){
      float4 wv = *(const float4*)(Wrow + f);
      float4 aa = *(const float4*)(av + f);
      acc += wv.x*aa.x + wv.y*aa.y + wv.z*aa.z + wv.w*aa.w;
    }
    vs[e] = acc;
  }
  __syncthreads();
  int n = blockIdx.x*blockDim.x + t;
  if (n >= N) return;
  float s[RELS], dd[RELS];
  #pragma unroll
  for (int r = 0; r < RELS; ++r){ s[r] = 0.f; dd[r] = 0.f; }
  const float* xr = x + (size_t)n*D;
  for (int k = 0; k < D; k += 4){
    float4 xv = *(const float4*)(xr + k);
    #pragma unroll
    for (int r = 0; r < RELS; ++r){
      s[r]  += xv.x*vs[r*D+k]   + xv.y*vs[r*D+k+1]   + xv.z*vs[r*D+k+2]   + xv.w*vs[r*D+k+3];
      dd[r] += xv.x*vs[512+r*D+k] + xv.y*vs[512+r*D+k+1]
             + xv.z*vs[512+r*D+k+2] + xv.w*vs[512+r*D+k+3];
    }
  }
  #pragma unroll
  for (int r = 0; r < RELS; ++r){
    float sv = s[r], dv = dd[r];
    s_all[(size_t)r*N + n] = sv;
    d_all[(size_t)r*N + n] = dv;
    float w = __expf(lrelu(sv + dv));
    wself[(size_t)r*N + n] = w;
    den[(size_t)r*N + n] = w;
  }
}

// ---- khist: count edges per fine key = dst*8 + rel
__global__ void khist(const int* __restrict__ dst, const int* __restrict__ et,
                      int* __restrict__ hist, int E){
  int stride = gridDim.x*blockDim.x;
  for (int i = blockIdx.x*blockDim.x+threadIdx.x; i < E; i += stride)
    atomicAdd(&hist[dst[i]*RELS + et[i]], 1);
}

// ---- 3-kernel exclusive scan: off[0..NK], off[0]=0; cur = copy
__global__ void kscan1(const int* __restrict__ hist, int* __restrict__ off,
                       int* __restrict__ bsums, int NK){
  __shared__ int tot[256];
  int b = blockIdx.x, t = threadIdx.x;
  int base = b*2048 + t*8;
  int v[8]; int c = 0;
  #pragma unroll
  for (int j = 0; j < 8; ++j){ int idx = base+j; int h = (idx<NK)? hist[idx]:0; c += h; v[j] = c; }
  tot[t] = c; __syncthreads();
  for (int o = 1; o < 256; o <<= 1){
    int add = (t >= o) ? tot[t-o] : 0;
    __syncthreads();
    tot[t] += add;
    __syncthreads();
  }
  int excl = (t == 0) ? 0 : tot[t-1];
  if (t == 255) bsums[b] = tot[255];
  #pragma unroll
  for (int j = 0; j < 8; ++j){ int idx = base+j; if (idx < NK) off[idx+1] = v[j] + excl; }
}

__global__ void kscan2(int* __restrict__ bsums, int NB){
  __shared__ int s[512];
  int t = threadIdx.x;
  s[t] = (t < NB) ? bsums[t] : 0;
  __syncthreads();
  for (int o = 1; o < 512; o <<= 1){
    int add = (t >= o) ? s[t-o] : 0;
    __syncthreads();
    s[t] += add;
    __syncthreads();
  }
  if (t < NB) bsums[t] = (t == 0) ? 0 : s[t-1];
}

__global__ void kscan3(int* __restrict__ off, int* __restrict__ cur,
                       const int* __restrict__ bsums, int NK){
  int b = blockIdx.x, t = threadIdx.x;
  int add = bsums[b];
  int base = b*2048 + t*8;
  #pragma unroll
  for (int j = 0; j < 8; ++j){
    int id1 = base+j+1;
    if (id1 <= NK){
      int nv = off[id1] + add;
      off[id1] = nv;
      if (id1 < NK) cur[id1] = nv;
    }
  }
  if (b == 0 && t == 0){ off[0] = 0; cur[0] = 0; }
}

// ---- kscatter: counting-sort by dst*8+rel; meta=(src, rel*N+dst); se=u; den += u
__global__ void kscatter(const int* __restrict__ src, const int* __restrict__ dst,
                         const int* __restrict__ et, const float* __restrict__ s_all,
                         const float* __restrict__ d_all, int* __restrict__ cur,
                         int2* __restrict__ meta, float* __restrict__ se,
                         float* __restrict__ den, int E, int N){
  int stride = gridDim.x*blockDim.x;
  for (int i = blockIdx.x*blockDim.x+threadIdx.x; i < E; i += stride){
    int r = et[i], dn = dst[i], sn = src[i];
    float e = lrelu(s_all[(size_t)r*N + sn] + d_all[(size_t)r*N + dn]);
    float u = __expf(e);
    int pos = atomicAdd(&cur[dn*RELS + r], 1);
    meta[pos] = make_int2(sn, r*N + dn);
    se[pos] = u;
    atomicAdd(&den[(size_t)r*N + dn], u);
  }
}

// ---- kinit: per 64-row tile: h_r = x@W_r (write bf16) and
// out = x@W_self + bsum + sum_r (wself/den)*h_r   (single write; no consumer GEMM)
__global__ __launch_bounds__(256) void kinit(const float* __restrict__ x,
    const float* __restrict__ W, const float* __restrict__ W_self,
    const float* __restrict__ b_self, const float* __restrict__ bias,
    const float* __restrict__ wself, const float* __restrict__ den,
    unsigned short* __restrict__ hb, float* __restrict__ out, int N){
  __shared__ float xs[64][68];
  int t = threadIdx.x;
  int row0 = blockIdx.x * 64;
  // stage x tile (4 threads per row, 16 cols each)
  {
    int srow = t >> 2, scq = (t & 3) * 16;
    bool rv = (row0 + srow) < N;
    float4 z4 = make_float4(0.f,0.f,0.f,0.f);
    const float* xp = x + (size_t)(row0+srow)*D + scq;
    #pragma unroll
    for (int j = 0; j < 4; ++j)
      *(float4*)(&xs[srow][scq + j*4]) = rv ? *(const float4*)(xp + j*4) : z4;
  }
  __syncthreads();

  int tcol = (t & 15) * 4, trow = (t >> 4) * 4;
  float acc[4][4] = {};

  for (int rel = 0; rel < RELS; ++rel){
    const float* B = W + (size_t)rel*D*D;
    float ha[4][4] = {};
    #pragma unroll 4
    for (int k4 = 0; k4 < 16; ++k4){
      int k = k4 << 2;
      float4 b0 = *(const float4*)(B + (k+0)*64 + tcol);
      float4 b1 = *(const float4*)(B + (k+1)*64 + tcol);
      float4 b2 = *(const float4*)(B + (k+2)*64 + tcol);
      float4 b3 = *(const float4*)(B + (k+3)*64 + tcol);
      #pragma unroll
      for (int j = 0; j < 4; ++j){
        float4 av = *(const float4*)(&xs[trow+j][k]);
        ha[j][0] += av.x*b0.x + av.y*b1.x + av.z*b2.x + av.w*b3.x;
        ha[j][1] += av.x*b0.y + av.y*b1.y + av.z*b2.y + av.w*b3.y;
        ha[j][2] += av.x*b0.z + av.y*b1.z + av.z*b2.z + av.w*b3.z;
        ha[j][3] += av.x*b0.w + av.y*b1.w + av.z*b2.w + av.w*b3.w;
      }
    }
    #pragma unroll
    for (int j = 0; j < 4; ++j){
      int row = row0 + trow + j;
      if (row < N){
        size_t rn = (size_t)rel*N + row;
        float sc = wself[rn] / den[rn];
        acc[j][0] += sc*ha[j][0]; acc[j][1] += sc*ha[j][1];
        acc[j][2] += sc*ha[j][2]; acc[j][3] += sc*ha[j][3];
        ushort4 hs = make_ushort4(f2bf(ha[j][0]), f2bf(ha[j][1]),
                                  f2bf(ha[j][2]), f2bf(ha[j][3]));
        *(ushort4*)(hb + rn*D + tcol) = hs;
      }
    }
  }
  // self-linear
  #pragma unroll 4
  for (int k4 = 0; k4 < 16; ++k4){
    int k = k4 << 2;
    float4 b0 = *(const float4*)(W_self + (k+0)*64 + tcol);
    float4 b1 = *(const float4*)(W_self + (k+1)*64 + tcol);
    float4 b2 = *(const float4*)(W_self + (k+2)*64 + tcol);
    float4 b3 = *(const float4*)(W_self + (k+3)*64 + tcol);
    #pragma unroll
    for (int j = 0; j < 4; ++j){
      float4 av = *(const float4*)(&xs[trow+j][k]);
      acc[j][0] += av.x*b0.x + av.y*b1.x + av.z*b2.x + av.w*b3.x;
      acc[j][1] += av.x*b0.y + av.y*b1.y + av.z*b2.y + av.w*b3.y;
      acc[j][2] += av.x*b0.z + av.y*b1.z + av.z*b2.z + av.w*b3.z;
      acc[j][3] += av.x*b0.w + av.y*b1.w + av.z*b2.w + av.w*b3.w;
    }
  }
  float4 bb = *(const float4*)(b_self + tcol);
  #pragma unroll
  for (int r = 0; r < RELS; ++r){
    float4 bv = *(const float4*)(bias + r*D + tcol);
    bb.x += bv.x; bb.y += bv.y; bb.z += bv.z; bb.w += bv.w;
  }
  #pragma unroll
  for (int j = 0; j < 4; ++j){
    int n = row0 + trow + j;
    if (n < N){
      float4 o = make_float4(acc[j][0]+bb.x, acc[j][1]+bb.y, acc[j][2]+bb.z, acc[j][3]+bb.w);
      *(float4*)(out + (size_t)n*D + tcol) = o;
    }
  }
}

// ---- kedge: wave exclusively owns node n; walks its contiguous edge range
// (all rels), accumulates alpha*h[src] in registers, single plain RMW on out.
__global__ __launch_bounds__(256) void kedge(const int2* __restrict__ meta,
    const float* __restrict__ se, const float* __restrict__ den,
    const unsigned short* __restrict__ hb, const int* __restrict__ off,
    float* __restrict__ out, int N){
  int gw = (blockIdx.x*blockDim.x + threadIdx.x) >> 6;
  if (gw >= N) return;
  int lane = threadIdx.x & 63;
  int n = gw;
  int k0 = off[n*RELS], k1 = off[n*RELS + RELS];
  float acc = 0.f;
  for (int i0 = k0; i0 < k1; i0 += 8){
    int cnt = k1 - i0;
    int lim = k1 - 1;
    int2 m[8]; float uu[8];
    #pragma unroll
    for (int j = 0; j < 8; ++j){
      int idx = min(i0 + j, lim);
      m[j] = meta[idx];
      uu[j] = se[idx];
    }
    float dd[8];
    #pragma unroll
    for (int j = 0; j < 8; ++j) dd[j] = den[m[j].y];
    unsigned short hv[8];
    #pragma unroll
    for (int j = 0; j < 8; ++j)
      hv[j] = hb[(size_t)(m[j].y - n + m[j].x)*D + lane];
    #pragma unroll
    for (int j = 0; j < 8; ++j)
      if (j < cnt) acc += (uu[j] / dd[j]) * bf2f(hv[j]);
  }
  float* op = out + (size_t)n*D + lane;
  *op += acc;
}

extern "C" void kernel_launch(void* const* d_in, const int* in_sizes, int n_in,
                              void* d_out, int out_size, void* d_ws, size_t ws_size,
                              hipStream_t stream) {
  const float* x      = (const float*)d_in[0];
  const int*   ei     = (const int*)d_in[1];
  const int*   et     = (const int*)d_in[2];
  const float* W_self = (const float*)d_in[3];
  const float* b_self = (const float*)d_in[4];
  const float* W      = (const float*)d_in[5];
  const float* a_src  = (const float*)d_in[6];
  const float* a_dst  = (const float*)d_in[7];
  const float* bias   = (const float*)d_in[8];

  int N = in_sizes[0] / D;
  int E = in_sizes[2];
  int NK = N * RELS;
  float* out = (float*)d_out;

  float* ws    = (float*)d_ws;
  float* s_all = ws;                           // NK
  float* d_all = s_all + (size_t)NK;           // NK
  float* wself = d_all + (size_t)NK;           // NK
  float* den   = wself + (size_t)NK;           // NK
  int* hist    = (int*)(den + (size_t)NK);     // NK
  int* off     = hist + (size_t)NK;            // NK+1 (+pad)
  int* cur     = off + (size_t)NK + 16;        // NK
  int* bsums   = cur + (size_t)NK;             // 512
  int2* meta   = (int2*)(bsums + 512);         // E
  float* se    = (float*)(meta + (size_t)E);   // E
  unsigned short* hb = (unsigned short*)(se + (size_t)E); // RELS*N*D bf16

  const int* srcp = ei;
  const int* dstp = ei + E;

  knode<<<(N + 255)/256, 256, 0, stream>>>(x, W, a_src, a_dst, s_all, d_all,
                                           wself, den, N);

  hipMemsetAsync(hist, 0, (size_t)NK*sizeof(int), stream);
  khist<<<2048, 256, 0, stream>>>(dstp, et, hist, E);

  int NB = (NK + 2047) / 2048;
  kscan1<<<NB, 256, 0, stream>>>(hist, off, bsums, NK);
  kscan2<<<1, 512, 0, stream>>>(bsums, NB);
  kscan3<<<NB, 256, 0, stream>>>(off, cur, bsums, NK);

  kscatter<<<2048, 256, 0, stream>>>(srcp, dstp, et, s_all, d_all, cur,
                                     meta, se, den, E, N);

  kinit<<<(N + 63)/64, 256, 0, stream>>>(x, W, W_self, b_self, bias,
                                         wself, den, hb, out, N);

  kedge<<<(N + 3)/4, 256, 0, stream>>>(meta, se, den, hb, off, out, N);
}